// Round 2
// baseline (980.838 us; speedup 1.0000x reference)
//
#include <hip/hip_runtime.h>
#include <math.h>

#define T_FRAMES 2000
#define B_BATCH  64
#define V_VOCAB  163
#define L_MAX    200
#define SPT      7            // states per lane; 64*7 = 448 >= S = 401
#define EBIAS    256          // renorm target: max scaled into [2^255, 2^256)

static_assert(64 * SPT >= 2 * L_MAX + 1, "state coverage");

#define L2E 1.4426950408889634f
#define LN2D 0.6931471805599453

__device__ __forceinline__ float wave_reduce_max(float v) {
#pragma unroll
  for (int i = 1; i < 64; i <<= 1) v = fmaxf(v, __shfl_xor(v, i, 64));
  return v;
}
__device__ __forceinline__ float wave_reduce_sum(float v) {
#pragma unroll
  for (int i = 1; i < 64; i <<= 1) v += __shfl_xor(v, i, 64);
  return v;
}
__device__ __forceinline__ double wave_reduce_max_d(double v) {
#pragma unroll
  for (int i = 1; i < 64; i <<= 1) v = fmax(v, __shfl_xor(v, i, 64));
  return v;
}

// probs[b][t][v] = softmax_v(logits[t][b][v]); transposed for contiguous per-chain streaming
__global__ __launch_bounds__(256) void softmax_tr_kernel(const float* __restrict__ logits,
                                                         float* __restrict__ probs) {
  int row = blockIdx.x * 4 + (threadIdx.x >> 6);
  if (row >= T_FRAMES * B_BATCH) return;
  int lane = threadIdx.x & 63;
  int t = row / B_BATCH;
  int b = row - t * B_BATCH;
  const float* __restrict__ src = logits + (size_t)row * V_VOCAB;
  float x0 = (lane < V_VOCAB) ? src[lane] : -1e30f;
  float x1 = (lane + 64 < V_VOCAB) ? src[lane + 64] : -1e30f;
  float x2 = (lane + 128 < V_VOCAB) ? src[lane + 128] : -1e30f;
  float mx = wave_reduce_max(fmaxf(fmaxf(x0, x1), x2));
  float e0 = exp2f((x0 - mx) * L2E);
  float e1 = exp2f((x1 - mx) * L2E);
  float e2 = exp2f((x2 - mx) * L2E);
  float inv = 1.0f / wave_reduce_sum(e0 + e1 + e2);
  float* __restrict__ dst = probs + ((size_t)b * T_FRAMES + t) * V_VOCAB;
  if (lane < V_VOCAB) dst[lane] = e0 * inv;
  if (lane + 64 < V_VOCAB) dst[lane + 64] = e1 * inv;
  if (lane + 128 < V_VOCAB) dst[lane + 128] = e2 * inv;
}

// fallback path: lse2[t*B+b] = log2(sum_v e^{logits}); pv = exp2(fma(x, L2E, -lse2))
__global__ __launch_bounds__(256) void lse_kernel(const float* __restrict__ logits,
                                                  float* __restrict__ lse2) {
  int row = blockIdx.x * 4 + (threadIdx.x >> 6);
  if (row >= T_FRAMES * B_BATCH) return;
  int lane = threadIdx.x & 63;
  const float* __restrict__ src = logits + (size_t)row * V_VOCAB;
  float x0 = (lane < V_VOCAB) ? src[lane] : -1e30f;
  float x1 = (lane + 64 < V_VOCAB) ? src[lane + 64] : -1e30f;
  float x2 = (lane + 128 < V_VOCAB) ? src[lane + 128] : -1e30f;
  float mx = wave_reduce_max(fmaxf(fmaxf(x0, x1), x2));
  float ssum = wave_reduce_sum(exp2f((x0 - mx) * L2E) + exp2f((x1 - mx) * L2E) +
                               exp2f((x2 - mx) * L2E));
  if (lane == 0) lse2[row] = mx * L2E + log2f(ssum);
}

// One block (one wave) per batch element. Prob-space forward recursion with the
// alpha vector in FP64 (window below running max ~886 nats with EBIAS=256 —
// fp32's 103-nat window severed completable paths ~230 nats/utt of error).
// Renorm = exact power-of-2 scale every 8 steps; probs stay fp32.
template <bool USE_PROBS>
__global__ __launch_bounds__(64) void ctc_kernel(const float* __restrict__ mat,
                                                 const float* __restrict__ lse2,
                                                 const int* __restrict__ labels,
                                                 const int* __restrict__ act_lens,
                                                 const int* __restrict__ label_lens,
                                                 float* __restrict__ losses) {
  const int b = blockIdx.x;
  const int lane = threadIdx.x;
  const int act_len = act_lens[b];
  const int LL = label_lens[b];
  const int send = 2 * LL;  // last valid extended state
  const int* __restrict__ lb = labels + b * L_MAX;

  // Per-lane constant state descriptors: gather offsets + skip-transition masks.
  // States s > send carry garbage mass (transitions only flow upward, so they
  // never reach sh[send]/sh[send-1]; renorm max including them is harmless).
  int off[SPT];
  double m2[SPT];
#pragma unroll
  for (int j = 0; j < SPT; ++j) {
    int s = lane * SPT + j;
    bool odd = (s & 1) != 0;
    int k = odd ? ((s - 1) >> 1) : 0;
    int kc = (k < L_MAX) ? k : (L_MAX - 1);
    int lab = odd ? lb[kc] : 0;  // even states are blank (0)
    off[j] = lab;
    bool skip = odd && (k >= 1) && (lab != lb[kc - 1]);
    m2[j] = skip ? 1.0 : 0.0;
  }

  auto rowptr = [&](int row) -> const float* {
    if (USE_PROBS) return mat + ((size_t)b * T_FRAMES + row) * V_VOCAB;
    else           return mat + ((size_t)row * B_BATCH + b) * V_VOCAB;
  };
  auto getnls = [&](int row) -> float {
    if (USE_PROBS) return 0.0f;
    else           return -lse2[row * B_BATCH + b];
  };

  // alpha in probability space (fp64), true_alpha = a * 2^{LS}
  double a[SPT];
  {
    const float* r0 = rowptr(0);
    float nls0 = getnls(0);
#pragma unroll
    for (int j = 0; j < SPT; ++j) {
      int s = lane * SPT + j;
      double p = 0.0;
      if (s < 2 && s <= send) {
        float x = r0[off[j]];
        p = (double)(USE_PROBS ? x : exp2f(fmaf(x, L2E, nls0)));
      }
      a[j] = p;
    }
  }

  auto issue = [&](int row, float (&P)[SPT]) {
    const float* rp = rowptr(row);
#pragma unroll
    for (int j = 0; j < SPT; ++j) P[j] = rp[off[j]];
  };

  auto step = [&](const float (&P)[SPT], float nls) {
    double prev1 = __shfl_up(a[SPT - 1], 1, 64);  // alpha[7*lane - 1]
    double prev2 = __shfl_up(a[SPT - 2], 1, 64);  // alpha[7*lane - 2]
    if (lane == 0) { prev1 = 0.0; prev2 = 0.0; }  // s=0 has no s-1 predecessor
    double n[SPT];
#pragma unroll
    for (int j = 0; j < SPT; ++j) {
      double s1 = (j >= 1) ? a[j - 1] : prev1;
      double s2 = (j >= 2) ? a[j - 2] : ((j == 1) ? prev1 : prev2);
      double pv = (double)(USE_PROBS ? P[j] : exp2f(fmaf(P[j], L2E, nls)));
      n[j] = fma(m2[j], s2, a[j] + s1) * pv;
    }
#pragma unroll
    for (int j = 0; j < SPT; ++j) a[j] = n[j];
  };

  int LS = 0;  // exact integer log2 scale: alpha_true = a * 2^{LS}
  auto renorm = [&]() {
    double m = a[0];
#pragma unroll
    for (int j = 1; j < SPT; ++j) m = fmax(m, a[j]);
    m = wave_reduce_max_d(m);
    long long bits = __double_as_longlong(m);
    int e2 = (int)((bits >> 52) & 0x7ff) - 1022;  // m in [2^(e2-1), 2^e2)
    int sc = e2 - EBIAS;                          // scale so max lands at 2^EBIAS
#pragma unroll
    for (int j = 0; j < SPT; ++j) a[j] = ldexp(a[j], -sc);
    LS += sc;
  };

  // double-buffered gathers, prefetched 2 steps ahead
  float PA[SPT], PB[SPT];
  float nlsA = 0.0f, nlsB = 0.0f;
  const int rowmax = T_FRAMES - 1;
  issue(1, PA); nlsA = getnls(1);
  { int r2 = (2 > rowmax) ? rowmax : 2; issue(r2, PB); nlsB = getnls(r2); }

  int t = 1;
  while (t + 8 <= act_len) {
#pragma unroll
    for (int u = 0; u < 8; u += 2) {
      step(PA, nlsA);
      { int r = t + u + 2; if (r > rowmax) r = rowmax; issue(r, PA); nlsA = getnls(r); }
      step(PB, nlsB);
      { int r = t + u + 3; if (r > rowmax) r = rowmax; issue(r, PB); nlsB = getnls(r); }
    }
    t += 8;
    renorm();
  }
  while (t < act_len) {  // tail <= 7 steps, synchronous loads, no renorm needed
    float P[SPT];
    issue(t, P);
    step(P, getnls(t));
    ++t;
  }

  __shared__ double sh[64 * SPT];
#pragma unroll
  for (int j = 0; j < SPT; ++j) sh[lane * SPT + j] = a[j];
  __syncthreads();
  if (lane == 0) {
    double ae = sh[send];
    double ap = (LL > 0) ? sh[send - 1] : 0.0;
    double s = ae + ap;
    losses[b] = (float)(-(log2(s) + (double)LS) * LN2D);
  }
}

__global__ __launch_bounds__(64) void finalize_kernel(const float* __restrict__ losses,
                                                      const int* __restrict__ act_lens,
                                                      float* __restrict__ out) {
  int lane = threadIdx.x;  // B == 64 exactly
  float l = losses[lane];
  float n = (float)act_lens[lane];
  l = wave_reduce_sum(l);
  n = wave_reduce_sum(n);
  if (lane == 0) out[0] = l / n;
}

extern "C" void kernel_launch(void* const* d_in, const int* in_sizes, int n_in,
                              void* d_out, int out_size, void* d_ws, size_t ws_size,
                              hipStream_t stream) {
  const float* logits = (const float*)d_in[0];
  const int* labels = (const int*)d_in[1];
  const int* act_lens = (const int*)d_in[2];
  const int* label_lens = (const int*)d_in[3];
  float* out = (float*)d_out;

  const size_t probs_bytes = (size_t)B_BATCH * T_FRAMES * V_VOCAB * sizeof(float);
  const int rows = T_FRAMES * B_BATCH;
  const int sm_grid = (rows + 3) / 4;

  if (ws_size >= probs_bytes + 1024) {
    float* probs = (float*)d_ws;
    float* losses = (float*)((char*)d_ws + probs_bytes);
    softmax_tr_kernel<<<dim3(sm_grid), dim3(256), 0, stream>>>(logits, probs);
    ctc_kernel<true><<<dim3(B_BATCH), dim3(64), 0, stream>>>(probs, nullptr, labels,
                                                             act_lens, label_lens, losses);
    finalize_kernel<<<dim3(1), dim3(64), 0, stream>>>(losses, act_lens, out);
  } else {
    float* lse2 = (float*)d_ws;  // rows floats = 512 KB
    float* losses = (float*)((char*)d_ws + (size_t)rows * sizeof(float));
    lse_kernel<<<dim3(sm_grid), dim3(256), 0, stream>>>(logits, lse2);
    ctc_kernel<false><<<dim3(B_BATCH), dim3(64), 0, stream>>>(logits, lse2, labels,
                                                              act_lens, label_lens, losses);
    finalize_kernel<<<dim3(1), dim3(64), 0, stream>>>(losses, act_lens, out);
  }
}

// Round 3
// 445.470 us; speedup vs baseline: 2.2018x; 2.2018x over previous
//
#include <hip/hip_runtime.h>
#include <math.h>

#define T_FRAMES 2000
#define B_BATCH  64
#define V_VOCAB  163
#define L_MAX    200
#define SPT      7            // states per lane; 64*7 = 448 >= S = 401
#define EBIAS    256          // renorm target: max scaled into [2^255, 2^256)
#define PFD      8            // prefetch depth (rows in flight; 8*7=56 loads < 63 vmcnt)

static_assert(64 * SPT >= 2 * L_MAX + 1, "state coverage");

#define L2E 1.4426950408889634f
#define LN2D 0.6931471805599453

__device__ __forceinline__ float wave_reduce_max(float v) {
#pragma unroll
  for (int i = 1; i < 64; i <<= 1) v = fmaxf(v, __shfl_xor(v, i, 64));
  return v;
}
__device__ __forceinline__ float wave_reduce_sum(float v) {
#pragma unroll
  for (int i = 1; i < 64; i <<= 1) v += __shfl_xor(v, i, 64);
  return v;
}
__device__ __forceinline__ double wave_reduce_max_d(double v) {
#pragma unroll
  for (int i = 1; i < 64; i <<= 1) v = fmax(v, __shfl_xor(v, i, 64));
  return v;
}

// probs[b][t][v] = softmax_v(logits[t][b][v]); transposed for contiguous per-chain streaming
__global__ __launch_bounds__(256) void softmax_tr_kernel(const float* __restrict__ logits,
                                                         float* __restrict__ probs) {
  int row = blockIdx.x * 4 + (threadIdx.x >> 6);
  if (row >= T_FRAMES * B_BATCH) return;
  int lane = threadIdx.x & 63;
  int t = row / B_BATCH;
  int b = row - t * B_BATCH;
  const float* __restrict__ src = logits + (size_t)row * V_VOCAB;
  float x0 = (lane < V_VOCAB) ? src[lane] : -1e30f;
  float x1 = (lane + 64 < V_VOCAB) ? src[lane + 64] : -1e30f;
  float x2 = (lane + 128 < V_VOCAB) ? src[lane + 128] : -1e30f;
  float mx = wave_reduce_max(fmaxf(fmaxf(x0, x1), x2));
  float e0 = exp2f((x0 - mx) * L2E);
  float e1 = exp2f((x1 - mx) * L2E);
  float e2 = exp2f((x2 - mx) * L2E);
  float inv = 1.0f / wave_reduce_sum(e0 + e1 + e2);
  float* __restrict__ dst = probs + ((size_t)b * T_FRAMES + t) * V_VOCAB;
  if (lane < V_VOCAB) dst[lane] = e0 * inv;
  if (lane + 64 < V_VOCAB) dst[lane + 64] = e1 * inv;
  if (lane + 128 < V_VOCAB) dst[lane + 128] = e2 * inv;
}

// fallback path: lse2[t*B+b] = log2(sum_v e^{logits}); pv = exp2(fma(x, L2E, -lse2))
__global__ __launch_bounds__(256) void lse_kernel(const float* __restrict__ logits,
                                                  float* __restrict__ lse2) {
  int row = blockIdx.x * 4 + (threadIdx.x >> 6);
  if (row >= T_FRAMES * B_BATCH) return;
  int lane = threadIdx.x & 63;
  const float* __restrict__ src = logits + (size_t)row * V_VOCAB;
  float x0 = (lane < V_VOCAB) ? src[lane] : -1e30f;
  float x1 = (lane + 64 < V_VOCAB) ? src[lane + 64] : -1e30f;
  float x2 = (lane + 128 < V_VOCAB) ? src[lane + 128] : -1e30f;
  float mx = wave_reduce_max(fmaxf(fmaxf(x0, x1), x2));
  float ssum = wave_reduce_sum(exp2f((x0 - mx) * L2E) + exp2f((x1 - mx) * L2E) +
                               exp2f((x2 - mx) * L2E));
  if (lane == 0) lse2[row] = mx * L2E + log2f(ssum);
}

// One block (one wave) per batch element. FP64 prob-space forward recursion,
// exact pow2 renorm every PFD steps. Round-2 was latency-bound (1030 cyc/step,
// VALUBusy 0.77%): prefetch distance 2 hid only ~130 of ~900 cyc gather latency.
// Now: rotating PFD=8-row register pipeline (56 loads in flight, load->use
// distance ~7 steps > HBM latency) + early next-step shuffles so ds_bpermute
// latency overlaps lanes 0..4 FMA work.
template <bool USE_PROBS>
__global__ __launch_bounds__(64) void ctc_kernel(const float* __restrict__ mat,
                                                 const float* __restrict__ lse2,
                                                 const int* __restrict__ labels,
                                                 const int* __restrict__ act_lens,
                                                 const int* __restrict__ label_lens,
                                                 float* __restrict__ losses) {
  const int b = blockIdx.x;
  const int lane = threadIdx.x;
  const int act_len = act_lens[b];
  const int LL = label_lens[b];
  const int send = 2 * LL;  // last valid extended state
  const int* __restrict__ lb = labels + b * L_MAX;

  // Per-lane constant state descriptors. States s > send carry garbage mass;
  // transitions only flow upward so they never reach sh[send]/sh[send-1].
  int off[SPT];
  double m2[SPT];
#pragma unroll
  for (int j = 0; j < SPT; ++j) {
    int s = lane * SPT + j;
    bool odd = (s & 1) != 0;
    int k = odd ? ((s - 1) >> 1) : 0;
    int kc = (k < L_MAX) ? k : (L_MAX - 1);
    int lab = odd ? lb[kc] : 0;  // even states are blank (0)
    off[j] = lab;
    bool skip = odd && (k >= 1) && (lab != lb[kc - 1]);
    m2[j] = skip ? 1.0 : 0.0;
  }

  auto rowptr = [&](int row) -> const float* {
    if (USE_PROBS) return mat + ((size_t)b * T_FRAMES + row) * V_VOCAB;
    else           return mat + ((size_t)row * B_BATCH + b) * V_VOCAB;
  };

  // alpha in probability space (fp64), true_alpha = a * 2^{LS}
  double a[SPT];
  {
    const float* r0 = rowptr(0);
    float nls0 = USE_PROBS ? 0.0f : -lse2[0 * B_BATCH + b];
#pragma unroll
    for (int j = 0; j < SPT; ++j) {
      int s = lane * SPT + j;
      double p = 0.0;
      if (s < 2 && s <= send) {
        float x = r0[off[j]];
        p = (double)(USE_PROBS ? x : exp2f(fmaf(x, L2E, nls0)));
      }
      a[j] = p;
    }
  }

  const int rowmax = T_FRAMES - 1;

  // rotating prefetch pipeline: PF[p] holds row t+p (all indices static)
  float PF[PFD][SPT];
  float NLS[PFD];
  auto issue = [&](int row, int p) {
    int r = (row > rowmax) ? rowmax : row;
    const float* rp = rowptr(r);
#pragma unroll
    for (int j = 0; j < SPT; ++j) PF[p][j] = rp[off[j]];
    NLS[p] = USE_PROBS ? 0.0f : -lse2[r * B_BATCH + b];
  };

  double prev1, prev2;  // alpha[7*lane-1], alpha[7*lane-2] from previous step
  const bool l0 = (lane == 0);

  auto step = [&](int p) {
    double pv[SPT];
#pragma unroll
    for (int j = 0; j < SPT; ++j)
      pv[j] = (double)(USE_PROBS ? PF[p][j] : exp2f(fmaf(PF[p][j], L2E, NLS[p])));
    // top two states first so next step's shuffles issue early
    double n5 = fma(m2[5], a[3], a[5] + a[4]) * pv[5];
    double n6 = fma(m2[6], a[4], a[6] + a[5]) * pv[6];
    double n0 = fma(m2[0], prev2, a[0] + prev1) * pv[0];
    double n1 = fma(m2[1], prev1, a[1] + a[0]) * pv[1];
    double n2 = fma(m2[2], a[0], a[2] + a[1]) * pv[2];
    double n3 = fma(m2[3], a[1], a[3] + a[2]) * pv[3];
    double n4 = fma(m2[4], a[2], a[4] + a[3]) * pv[4];
    a[5] = n5; a[6] = n6;
    double np1 = __shfl_up(a[6], 1, 64);
    double np2 = __shfl_up(a[5], 1, 64);
    a[0] = n0; a[1] = n1; a[2] = n2; a[3] = n3; a[4] = n4;
    prev1 = l0 ? 0.0 : np1;
    prev2 = l0 ? 0.0 : np2;
  };

  int LS = 0;  // exact integer log2 scale: alpha_true = a * 2^{LS}
  auto renorm = [&]() {
    double m = a[0];
#pragma unroll
    for (int j = 1; j < SPT; ++j) m = fmax(m, a[j]);
    m = wave_reduce_max_d(m);
    long long bits = __double_as_longlong(m);
    int e2 = (int)((bits >> 52) & 0x7ff) - 1022;  // m in [2^(e2-1), 2^e2)
    int sc = e2 - EBIAS;                          // scale so max lands at 2^EBIAS
#pragma unroll
    for (int j = 0; j < SPT; ++j) a[j] = ldexp(a[j], -sc);
    prev1 = ldexp(prev1, -sc);  // carried shuffle values live in alpha space
    prev2 = ldexp(prev2, -sc);
    LS += sc;
  };

  // prologue: fill pipeline with rows 1..PFD, prime shuffles from alpha0
#pragma unroll
  for (int d = 0; d < PFD; ++d) issue(1 + d, d);
  {
    double np1 = __shfl_up(a[SPT - 1], 1, 64);
    double np2 = __shfl_up(a[SPT - 2], 1, 64);
    prev1 = l0 ? 0.0 : np1;
    prev2 = l0 ? 0.0 : np2;
  }

  int t = 1;
  while (t + PFD <= act_len) {
#pragma unroll
    for (int p = 0; p < PFD; ++p) {
      step(p);               // consumes row t+p
      issue(t + p + PFD, p); // refill with row t+p+PFD
    }
    t += PFD;
    renorm();
  }
  // tail: rows t..act_len-1 already resident in PF[0..]; <= PFD-1 steps, no renorm needed
#pragma unroll
  for (int p = 0; p < PFD; ++p) {
    if (t + p < act_len) step(p);
  }

  __shared__ double sh[64 * SPT];
#pragma unroll
  for (int j = 0; j < SPT; ++j) sh[lane * SPT + j] = a[j];
  __syncthreads();
  if (lane == 0) {
    double ae = sh[send];
    double ap = (LL > 0) ? sh[send - 1] : 0.0;
    double s = ae + ap;
    losses[b] = (float)(-(log2(s) + (double)LS) * LN2D);
  }
}

__global__ __launch_bounds__(64) void finalize_kernel(const float* __restrict__ losses,
                                                      const int* __restrict__ act_lens,
                                                      float* __restrict__ out) {
  int lane = threadIdx.x;  // B == 64 exactly
  float l = losses[lane];
  float n = (float)act_lens[lane];
  l = wave_reduce_sum(l);
  n = wave_reduce_sum(n);
  if (lane == 0) out[0] = l / n;
}

extern "C" void kernel_launch(void* const* d_in, const int* in_sizes, int n_in,
                              void* d_out, int out_size, void* d_ws, size_t ws_size,
                              hipStream_t stream) {
  const float* logits = (const float*)d_in[0];
  const int* labels = (const int*)d_in[1];
  const int* act_lens = (const int*)d_in[2];
  const int* label_lens = (const int*)d_in[3];
  float* out = (float*)d_out;

  const size_t probs_bytes = (size_t)B_BATCH * T_FRAMES * V_VOCAB * sizeof(float);
  const int rows = T_FRAMES * B_BATCH;
  const int sm_grid = (rows + 3) / 4;

  if (ws_size >= probs_bytes + 1024) {
    float* probs = (float*)d_ws;
    float* losses = (float*)((char*)d_ws + probs_bytes);
    softmax_tr_kernel<<<dim3(sm_grid), dim3(256), 0, stream>>>(logits, probs);
    ctc_kernel<true><<<dim3(B_BATCH), dim3(64), 0, stream>>>(probs, nullptr, labels,
                                                             act_lens, label_lens, losses);
    finalize_kernel<<<dim3(1), dim3(64), 0, stream>>>(losses, act_lens, out);
  } else {
    float* lse2 = (float*)d_ws;  // rows floats = 512 KB
    float* losses = (float*)((char*)d_ws + (size_t)rows * sizeof(float));
    lse_kernel<<<dim3(sm_grid), dim3(256), 0, stream>>>(logits, lse2);
    ctc_kernel<false><<<dim3(B_BATCH), dim3(64), 0, stream>>>(logits, lse2, labels,
                                                              act_lens, label_lens, losses);
    finalize_kernel<<<dim3(1), dim3(64), 0, stream>>>(losses, act_lens, out);
  }
}

// Round 5
// 426.822 us; speedup vs baseline: 2.2980x; 1.0437x over previous
//
#include <hip/hip_runtime.h>
#include <math.h>

#define T_FRAMES 2000
#define B_BATCH  64
#define V_VOCAB  163
#define L_MAX    200
#define SPT      7            // states per lane; 64*7 = 448 >= S = 401
#define EBIAS    320          // renorm target: max scaled into [2^319, 2^320)
#define PFD      8            // prefetch depth (rows in flight; 8*7=56 loads < 63 vmcnt)

static_assert(64 * SPT >= 2 * L_MAX + 1, "state coverage");

#define L2E 1.4426950408889634f
#define LN2D 0.6931471805599453

__device__ __forceinline__ float wave_reduce_max(float v) {
#pragma unroll
  for (int i = 1; i < 64; i <<= 1) v = fmaxf(v, __shfl_xor(v, i, 64));
  return v;
}
__device__ __forceinline__ float wave_reduce_sum(float v) {
#pragma unroll
  for (int i = 1; i < 64; i <<= 1) v += __shfl_xor(v, i, 64);
  return v;
}
__device__ __forceinline__ int wave_reduce_max_i(int v) {
#pragma unroll
  for (int i = 1; i < 64; i <<= 1) v = max(v, __shfl_xor(v, i, 64));
  return v;
}

// probs[b][t][v] = softmax_v(logits[t][b][v]); transposed for contiguous per-chain streaming
__global__ __launch_bounds__(256) void softmax_tr_kernel(const float* __restrict__ logits,
                                                         float* __restrict__ probs) {
  int row = blockIdx.x * 4 + (threadIdx.x >> 6);
  if (row >= T_FRAMES * B_BATCH) return;
  int lane = threadIdx.x & 63;
  int t = row / B_BATCH;
  int b = row - t * B_BATCH;
  const float* __restrict__ src = logits + (size_t)row * V_VOCAB;
  float x0 = (lane < V_VOCAB) ? src[lane] : -1e30f;
  float x1 = (lane + 64 < V_VOCAB) ? src[lane + 64] : -1e30f;
  float x2 = (lane + 128 < V_VOCAB) ? src[lane + 128] : -1e30f;
  float mx = wave_reduce_max(fmaxf(fmaxf(x0, x1), x2));
  float e0 = exp2f((x0 - mx) * L2E);
  float e1 = exp2f((x1 - mx) * L2E);
  float e2 = exp2f((x2 - mx) * L2E);
  float inv = 1.0f / wave_reduce_sum(e0 + e1 + e2);
  float* __restrict__ dst = probs + ((size_t)b * T_FRAMES + t) * V_VOCAB;
  if (lane < V_VOCAB) dst[lane] = e0 * inv;
  if (lane + 64 < V_VOCAB) dst[lane + 64] = e1 * inv;
  if (lane + 128 < V_VOCAB) dst[lane + 128] = e2 * inv;
}

// fallback path: lse2[t*B+b] = log2(sum_v e^{logits}); pv = exp2(fma(x, L2E, -lse2))
__global__ __launch_bounds__(256) void lse_kernel(const float* __restrict__ logits,
                                                  float* __restrict__ lse2) {
  int row = blockIdx.x * 4 + (threadIdx.x >> 6);
  if (row >= T_FRAMES * B_BATCH) return;
  int lane = threadIdx.x & 63;
  const float* __restrict__ src = logits + (size_t)row * V_VOCAB;
  float x0 = (lane < V_VOCAB) ? src[lane] : -1e30f;
  float x1 = (lane + 64 < V_VOCAB) ? src[lane + 64] : -1e30f;
  float x2 = (lane + 128 < V_VOCAB) ? src[lane + 128] : -1e30f;
  float mx = wave_reduce_max(fmaxf(fmaxf(x0, x1), x2));
  float ssum = wave_reduce_sum(exp2f((x0 - mx) * L2E) + exp2f((x1 - mx) * L2E) +
                               exp2f((x2 - mx) * L2E));
  if (lane == 0) lse2[row] = mx * L2E + log2f(ssum);
}

// One block (one wave) per batch element. FP64 prob-space forward recursion.
// __launch_bounds__(64,1): allocator keeps the PFD=8 rotating prefetch buffer
// resident (round-3's default target collapsed it; VGPR_Count=72).
// Renorm every 16 steps, EBIAS=320. ROUND-4 BUG FIXED HERE: exponent must be
// read from the FP64 bit pattern — casting the max to f32 overflowed to +inf
// whenever max > 2^128 (guaranteed possible with EBIAS=320), making renorm
// scale UP by 2^191 in a feedback loop -> f64 inf -> fma(0,inf,..) = NaN.
template <bool USE_PROBS>
__global__ __launch_bounds__(64, 1) void ctc_kernel(const float* __restrict__ mat,
                                                    const float* __restrict__ lse2,
                                                    const int* __restrict__ labels,
                                                    const int* __restrict__ act_lens,
                                                    const int* __restrict__ label_lens,
                                                    float* __restrict__ losses) {
  const int b = blockIdx.x;
  const int lane = threadIdx.x;
  const int act_len = act_lens[b];
  const int LL = label_lens[b];
  const int send = 2 * LL;  // last valid extended state
  const int* __restrict__ lb = labels + b * L_MAX;

  // Per-lane constant state descriptors. States s > send carry harmless extra
  // mass; transitions only flow upward so it never reaches sh[send]/sh[send-1].
  int off[SPT];
  double m2[SPT];
#pragma unroll
  for (int j = 0; j < SPT; ++j) {
    int s = lane * SPT + j;
    bool odd = (s & 1) != 0;
    int k = odd ? ((s - 1) >> 1) : 0;
    int kc = (k < L_MAX) ? k : (L_MAX - 1);
    int lab = odd ? lb[kc] : 0;  // even states are blank (0)
    off[j] = lab;
    bool skip = odd && (k >= 1) && (lab != lb[kc - 1]);
    m2[j] = skip ? 1.0 : 0.0;
  }

  auto rowptr = [&](int row) -> const float* {
    if (USE_PROBS) return mat + ((size_t)b * T_FRAMES + row) * V_VOCAB;
    else           return mat + ((size_t)row * B_BATCH + b) * V_VOCAB;
  };

  // alpha in probability space (fp64), true_alpha = a * 2^{LS}
  double a[SPT];
  {
    const float* r0 = rowptr(0);
    float nls0 = USE_PROBS ? 0.0f : -lse2[0 * B_BATCH + b];
#pragma unroll
    for (int j = 0; j < SPT; ++j) {
      int s = lane * SPT + j;
      double p = 0.0;
      if (s < 2 && s <= send) {
        float x = r0[off[j]];
        p = (double)(USE_PROBS ? x : exp2f(fmaf(x, L2E, nls0)));
      }
      a[j] = p;
    }
  }

  const int rowmax = T_FRAMES - 1;

  // rotating prefetch pipeline: PF[p] holds row t+p (all indices static)
  float PF[PFD][SPT];
  float NLS[PFD];
  auto issue = [&](int row, int p) {
    int r = (row > rowmax) ? rowmax : row;
    const float* rp = rowptr(r);
#pragma unroll
    for (int j = 0; j < SPT; ++j) PF[p][j] = rp[off[j]];
    NLS[p] = USE_PROBS ? 0.0f : -lse2[r * B_BATCH + b];
  };

  double prev1, prev2;  // alpha[7*lane-1], alpha[7*lane-2] from previous step
  const bool l0 = (lane == 0);

  auto step = [&](int p) {
    double pv[SPT];
#pragma unroll
    for (int j = 0; j < SPT; ++j)
      pv[j] = (double)(USE_PROBS ? PF[p][j] : exp2f(fmaf(PF[p][j], L2E, NLS[p])));
    // top two states first so next step's shuffles issue early
    double n5 = fma(m2[5], a[3], a[5] + a[4]) * pv[5];
    double n6 = fma(m2[6], a[4], a[6] + a[5]) * pv[6];
    double n0 = fma(m2[0], prev2, a[0] + prev1) * pv[0];
    double n1 = fma(m2[1], prev1, a[1] + a[0]) * pv[1];
    double n2 = fma(m2[2], a[0], a[2] + a[1]) * pv[2];
    double n3 = fma(m2[3], a[1], a[3] + a[2]) * pv[3];
    double n4 = fma(m2[4], a[2], a[4] + a[3]) * pv[4];
    a[5] = n5; a[6] = n6;
    double np1 = __shfl_up(a[6], 1, 64);
    double np2 = __shfl_up(a[5], 1, 64);
    a[0] = n0; a[1] = n1; a[2] = n2; a[3] = n3; a[4] = n4;
    prev1 = l0 ? 0.0 : np1;
    prev2 = l0 ? 0.0 : np2;
  };

  int LS = 0;  // exact integer log2 scale: alpha_true = a * 2^{LS}
  auto renorm = [&]() {
    double m = a[0];
#pragma unroll
    for (int j = 1; j < SPT; ++j) m = fmax(m, a[j]);
    // exponent-only reduction on the FP64 bit pattern (int shuffles are cheap
    // AND correct for any f64 magnitude; f32 cast broke at max > 2^128)
    int eb = (int)(__double_as_longlong(m) >> 52);  // biased exponent, m >= 0
    eb = wave_reduce_max_i(eb);
    int sc = (eb - 1022) - EBIAS;  // scale so max lands near 2^EBIAS
#pragma unroll
    for (int j = 0; j < SPT; ++j) a[j] = ldexp(a[j], -sc);
    prev1 = ldexp(prev1, -sc);  // carried shuffle values live in alpha space
    prev2 = ldexp(prev2, -sc);
    LS += sc;
  };

  // prologue: fill pipeline with rows 1..PFD, prime shuffles from alpha0
#pragma unroll
  for (int d = 0; d < PFD; ++d) issue(1 + d, d);
  {
    double np1 = __shfl_up(a[SPT - 1], 1, 64);
    double np2 = __shfl_up(a[SPT - 2], 1, 64);
    prev1 = l0 ? 0.0 : np1;
    prev2 = l0 ? 0.0 : np2;
  }

  int t = 1;
  // main loop: 16 steps (two pipeline rotations) per renorm
  while (t + 2 * PFD <= act_len) {
#pragma unroll
    for (int p = 0; p < PFD; ++p) { step(p); issue(t + p + PFD, p); }
#pragma unroll
    for (int p = 0; p < PFD; ++p) { step(p); issue(t + PFD + p + PFD, p); }
    t += 2 * PFD;
    renorm();
  }
  while (t + PFD <= act_len) {
#pragma unroll
    for (int p = 0; p < PFD; ++p) { step(p); issue(t + p + PFD, p); }
    t += PFD;
    renorm();
  }
  // tail: rows t..act_len-1 already resident in PF[0..]; <= PFD-1 steps
#pragma unroll
  for (int p = 0; p < PFD; ++p) {
    if (t + p < act_len) step(p);
  }

  __shared__ double sh[64 * SPT];
#pragma unroll
  for (int j = 0; j < SPT; ++j) sh[lane * SPT + j] = a[j];
  __syncthreads();
  if (lane == 0) {
    double ae = sh[send];
    double ap = (LL > 0) ? sh[send - 1] : 0.0;
    double s = ae + ap;
    losses[b] = (float)(-(log2(s) + (double)LS) * LN2D);
  }
}

__global__ __launch_bounds__(64) void finalize_kernel(const float* __restrict__ losses,
                                                      const int* __restrict__ act_lens,
                                                      float* __restrict__ out) {
  int lane = threadIdx.x;  // B == 64 exactly
  float l = losses[lane];
  float n = (float)act_lens[lane];
  l = wave_reduce_sum(l);
  n = wave_reduce_sum(n);
  if (lane == 0) out[0] = l / n;
}

extern "C" void kernel_launch(void* const* d_in, const int* in_sizes, int n_in,
                              void* d_out, int out_size, void* d_ws, size_t ws_size,
                              hipStream_t stream) {
  const float* logits = (const float*)d_in[0];
  const int* labels = (const int*)d_in[1];
  const int* act_lens = (const int*)d_in[2];
  const int* label_lens = (const int*)d_in[3];
  float* out = (float*)d_out;

  const size_t probs_bytes = (size_t)B_BATCH * T_FRAMES * V_VOCAB * sizeof(float);
  const int rows = T_FRAMES * B_BATCH;
  const int sm_grid = (rows + 3) / 4;

  if (ws_size >= probs_bytes + 1024) {
    float* probs = (float*)d_ws;
    float* losses = (float*)((char*)d_ws + probs_bytes);
    softmax_tr_kernel<<<dim3(sm_grid), dim3(256), 0, stream>>>(logits, probs);
    ctc_kernel<true><<<dim3(B_BATCH), dim3(64), 0, stream>>>(probs, nullptr, labels,
                                                             act_lens, label_lens, losses);
    finalize_kernel<<<dim3(1), dim3(64), 0, stream>>>(losses, act_lens, out);
  } else {
    float* lse2 = (float*)d_ws;  // rows floats = 512 KB
    float* losses = (float*)((char*)d_ws + (size_t)rows * sizeof(float));
    lse_kernel<<<dim3(sm_grid), dim3(256), 0, stream>>>(logits, lse2);
    ctc_kernel<false><<<dim3(B_BATCH), dim3(64), 0, stream>>>(logits, lse2, labels,
                                                              act_lens, label_lens, losses);
    finalize_kernel<<<dim3(1), dim3(64), 0, stream>>>(losses, act_lens, out);
  }
}

// Round 6
// 400.642 us; speedup vs baseline: 2.4482x; 1.0653x over previous
//
#include <hip/hip_runtime.h>
#include <math.h>

#define T_FRAMES 2000
#define B_BATCH  64
#define V_VOCAB  163
#define L_MAX    200
#define SPT      7            // states per lane; 64*7 = 448 >= S = 401
#define EBIAS    320          // renorm target: max scaled into [2^319, 2^320)
#define PFD      8            // prefetch depth: 8 rows * 7 loads = 56 in flight (< vmcnt max 63)

static_assert(64 * SPT >= 2 * L_MAX + 1, "state coverage");

#define L2E 1.4426950408889634f
#define LN2D 0.6931471805599453

__device__ __forceinline__ float wave_reduce_max(float v) {
#pragma unroll
  for (int i = 1; i < 64; i <<= 1) v = fmaxf(v, __shfl_xor(v, i, 64));
  return v;
}
__device__ __forceinline__ float wave_reduce_sum(float v) {
#pragma unroll
  for (int i = 1; i < 64; i <<= 1) v += __shfl_xor(v, i, 64);
  return v;
}
__device__ __forceinline__ int wave_reduce_max_i(int v) {
#pragma unroll
  for (int i = 1; i < 64; i <<= 1) v = max(v, __shfl_xor(v, i, 64));
  return v;
}

// probs[b][t][v] = softmax_v(logits[t][b][v]); transposed for contiguous per-chain streaming
__global__ __launch_bounds__(256) void softmax_tr_kernel(const float* __restrict__ logits,
                                                         float* __restrict__ probs) {
  int row = blockIdx.x * 4 + (threadIdx.x >> 6);
  if (row >= T_FRAMES * B_BATCH) return;
  int lane = threadIdx.x & 63;
  int t = row / B_BATCH;
  int b = row - t * B_BATCH;
  const float* __restrict__ src = logits + (size_t)row * V_VOCAB;
  float x0 = (lane < V_VOCAB) ? src[lane] : -1e30f;
  float x1 = (lane + 64 < V_VOCAB) ? src[lane + 64] : -1e30f;
  float x2 = (lane + 128 < V_VOCAB) ? src[lane + 128] : -1e30f;
  float mx = wave_reduce_max(fmaxf(fmaxf(x0, x1), x2));
  float e0 = exp2f((x0 - mx) * L2E);
  float e1 = exp2f((x1 - mx) * L2E);
  float e2 = exp2f((x2 - mx) * L2E);
  float inv = 1.0f / wave_reduce_sum(e0 + e1 + e2);
  float* __restrict__ dst = probs + ((size_t)b * T_FRAMES + t) * V_VOCAB;
  if (lane < V_VOCAB) dst[lane] = e0 * inv;
  if (lane + 64 < V_VOCAB) dst[lane + 64] = e1 * inv;
  if (lane + 128 < V_VOCAB) dst[lane + 128] = e2 * inv;
}

// fallback path: lse2[t*B+b] = log2(sum_v e^{logits}); pv = exp2(fma(x, L2E, -lse2))
__global__ __launch_bounds__(256) void lse_kernel(const float* __restrict__ logits,
                                                  float* __restrict__ lse2) {
  int row = blockIdx.x * 4 + (threadIdx.x >> 6);
  if (row >= T_FRAMES * B_BATCH) return;
  int lane = threadIdx.x & 63;
  const float* __restrict__ src = logits + (size_t)row * V_VOCAB;
  float x0 = (lane < V_VOCAB) ? src[lane] : -1e30f;
  float x1 = (lane + 64 < V_VOCAB) ? src[lane + 64] : -1e30f;
  float x2 = (lane + 128 < V_VOCAB) ? src[lane + 128] : -1e30f;
  float mx = wave_reduce_max(fmaxf(fmaxf(x0, x1), x2));
  float ssum = wave_reduce_sum(exp2f((x0 - mx) * L2E) + exp2f((x1 - mx) * L2E) +
                               exp2f((x2 - mx) * L2E));
  if (lane == 0) lse2[row] = mx * L2E + log2f(ssum);
}

// ---- hand-controlled prefetch primitives -----------------------------------
// Round-5 post-mortem: the machine scheduler sinks compiler-visible prefetch
// loads to their uses even with __launch_bounds__(64,1) (VGPR stayed 72; ~237
// cyc/step stall = one L3-hit latency). Volatile asm loads cannot be sunk or
// rematerialized, and explicit vmcnt waits (values tied via "+v" so consumers
// can't hoist above the wait) give exact FIFO pipeline control. All VMEM in
// the steady loop is issued here, so the vmcnt arithmetic is exact.
__device__ __forceinline__ void gload(float& dst, int voff, const float* sbase) {
  asm volatile("global_load_dword %0, %1, %2"
               : "=v"(dst)
               : "v"(voff), "s"(sbase));
}
template <int N>
__device__ __forceinline__ void wait_slot(float (&f)[SPT]) {
  asm volatile("s_waitcnt vmcnt(%7)"
               : "+v"(f[0]), "+v"(f[1]), "+v"(f[2]), "+v"(f[3]),
                 "+v"(f[4]), "+v"(f[5]), "+v"(f[6])
               : "i"(N));
}

// One block (one wave) per batch element. FP64 prob-space forward recursion,
// exact pow2 renorm every 8 steps (EBIAS=320; exponent read from the FP64 bit
// pattern — round-4's f32 cast overflowed at max > 2^128).
__global__ __launch_bounds__(64, 1) void ctc_kernel_probs(const float* __restrict__ mat,
                                                          const int* __restrict__ labels,
                                                          const int* __restrict__ act_lens,
                                                          const int* __restrict__ label_lens,
                                                          float* __restrict__ losses) {
  const int b = blockIdx.x;
  const int lane = threadIdx.x;
  const int act_len = act_lens[b];
  const int LL = label_lens[b];
  const int send = 2 * LL;  // last valid extended state
  const int* __restrict__ lb = labels + b * L_MAX;

  // Per-lane constant state descriptors. States s > send carry harmless extra
  // mass; transitions only flow upward so it never reaches sh[send]/sh[send-1].
  int voff[SPT];
  double m2[SPT];
#pragma unroll
  for (int j = 0; j < SPT; ++j) {
    int s = lane * SPT + j;
    bool odd = (s & 1) != 0;
    int k = odd ? ((s - 1) >> 1) : 0;
    int kc = (k < L_MAX) ? k : (L_MAX - 1);
    int lab = odd ? lb[kc] : 0;  // even states are blank (0)
    voff[j] = lab * 4;           // byte offset for asm gather
    bool skip = odd && (k >= 1) && (lab != lb[kc - 1]);
    m2[j] = skip ? 1.0 : 0.0;
  }

  const float* __restrict__ chain = mat + (size_t)b * T_FRAMES * V_VOCAB;

  // alpha in probability space (fp64), true_alpha = a * 2^{LS}
  double a[SPT];
#pragma unroll
  for (int j = 0; j < SPT; ++j) {
    int s = lane * SPT + j;
    double p = 0.0;
    if (s < 2 && s <= send) p = (double)chain[voff[j] >> 2];  // row 0
    a[j] = p;
  }

  double prev1, prev2;  // alpha[7*lane-1], alpha[7*lane-2] from previous step
  const bool l0 = (lane == 0);

  float PF[PFD][SPT];

  auto step = [&](int p) {
    double pv[SPT];
#pragma unroll
    for (int j = 0; j < SPT; ++j) pv[j] = (double)PF[p][j];
    double n5 = fma(m2[5], a[3], a[5] + a[4]) * pv[5];
    double n6 = fma(m2[6], a[4], a[6] + a[5]) * pv[6];
    double n0 = fma(m2[0], prev2, a[0] + prev1) * pv[0];
    double n1 = fma(m2[1], prev1, a[1] + a[0]) * pv[1];
    double n2 = fma(m2[2], a[0], a[2] + a[1]) * pv[2];
    double n3 = fma(m2[3], a[1], a[3] + a[2]) * pv[3];
    double n4 = fma(m2[4], a[2], a[4] + a[3]) * pv[4];
    a[5] = n5; a[6] = n6;
    double np1 = __shfl_up(a[6], 1, 64);
    double np2 = __shfl_up(a[5], 1, 64);
    a[0] = n0; a[1] = n1; a[2] = n2; a[3] = n3; a[4] = n4;
    prev1 = l0 ? 0.0 : np1;
    prev2 = l0 ? 0.0 : np2;
  };

  int LS = 0;  // exact integer log2 scale: alpha_true = a * 2^{LS}
  auto renorm = [&]() {
    double m = a[0];
#pragma unroll
    for (int j = 1; j < SPT; ++j) m = fmax(m, a[j]);
    int eb = (int)(__double_as_longlong(m) >> 52);  // biased exponent, m >= 0
    eb = wave_reduce_max_i(eb);
    int sc = (eb - 1022) - EBIAS;  // scale so max lands near 2^EBIAS
#pragma unroll
    for (int j = 0; j < SPT; ++j) a[j] = ldexp(a[j], -sc);
    prev1 = ldexp(prev1, -sc);
    prev2 = ldexp(prev2, -sc);
    LS += sc;
  };

  const float* bp = chain + (size_t)1 * V_VOCAB;                 // next row to issue
  const float* bmax = chain + (size_t)(T_FRAMES - 1) * V_VOCAB;  // clamp

  auto issue = [&](int p) {
    const float* rp = (bp > bmax) ? bmax : bp;
#pragma unroll
    for (int j = 0; j < SPT; ++j) gload(PF[p][j], voff[j], rp);
    bp += V_VOCAB;
  };

  // prologue: fill pipeline with rows 1..PFD; prime shuffles from alpha0
#pragma unroll
  for (int d = 0; d < PFD; ++d) issue(d);
  {
    double np1 = __shfl_up(a[SPT - 1], 1, 64);
    double np2 = __shfl_up(a[SPT - 2], 1, 64);
    prev1 = l0 ? 0.0 : np1;
    prev2 = l0 ? 0.0 : np2;
  }

  int t = 1;
  // steady state: slots 0..7 hold rows t..t+7; 56 loads outstanding.
  // wait vmcnt(49) completes the oldest slot's 7 loads (FIFO semantics).
  while (t + PFD <= act_len) {
#pragma unroll
    for (int p = 0; p < PFD; ++p) {
      wait_slot<49>(PF[p]);
      step(p);
      issue(p);
    }
    t += PFD;
    renorm();
  }
  // drain: R <= 7 rows remain, slot p holds row t+p; no new issues.
  {
    int R = act_len - t;
    if (R > 0) { wait_slot<49>(PF[0]); step(0); }
    if (R > 1) { wait_slot<42>(PF[1]); step(1); }
    if (R > 2) { wait_slot<35>(PF[2]); step(2); }
    if (R > 3) { wait_slot<28>(PF[3]); step(3); }
    if (R > 4) { wait_slot<21>(PF[4]); step(4); }
    if (R > 5) { wait_slot<14>(PF[5]); step(5); }
    if (R > 6) { wait_slot<7>(PF[6]); step(6); }
  }
  asm volatile("s_waitcnt vmcnt(0)");  // hygiene: retire leftover prefetches

  __shared__ double sh[64 * SPT];
#pragma unroll
  for (int j = 0; j < SPT; ++j) sh[lane * SPT + j] = a[j];
  __syncthreads();
  if (lane == 0) {
    double ae = sh[send];
    double ap = (LL > 0) ? sh[send - 1] : 0.0;
    double s = ae + ap;
    losses[b] = (float)(-(log2(s) + (double)LS) * LN2D);
  }
}

// Fallback (workspace too small for probs): round-5 structure, compiler-scheduled.
__global__ __launch_bounds__(64, 1) void ctc_kernel_lse(const float* __restrict__ mat,
                                                        const float* __restrict__ lse2,
                                                        const int* __restrict__ labels,
                                                        const int* __restrict__ act_lens,
                                                        const int* __restrict__ label_lens,
                                                        float* __restrict__ losses) {
  const int b = blockIdx.x;
  const int lane = threadIdx.x;
  const int act_len = act_lens[b];
  const int LL = label_lens[b];
  const int send = 2 * LL;
  const int* __restrict__ lb = labels + b * L_MAX;

  int off[SPT];
  double m2[SPT];
#pragma unroll
  for (int j = 0; j < SPT; ++j) {
    int s = lane * SPT + j;
    bool odd = (s & 1) != 0;
    int k = odd ? ((s - 1) >> 1) : 0;
    int kc = (k < L_MAX) ? k : (L_MAX - 1);
    int lab = odd ? lb[kc] : 0;
    off[j] = lab;
    bool skip = odd && (k >= 1) && (lab != lb[kc - 1]);
    m2[j] = skip ? 1.0 : 0.0;
  }

  auto rowptr = [&](int row) -> const float* {
    return mat + ((size_t)row * B_BATCH + b) * V_VOCAB;
  };

  double a[SPT];
  {
    const float* r0 = rowptr(0);
    float nls0 = -lse2[b];
#pragma unroll
    for (int j = 0; j < SPT; ++j) {
      int s = lane * SPT + j;
      double p = 0.0;
      if (s < 2 && s <= send) p = (double)exp2f(fmaf(r0[off[j]], L2E, nls0));
      a[j] = p;
    }
  }

  const int rowmax = T_FRAMES - 1;
  float PF[PFD][SPT];
  float NLS[PFD];
  auto issue = [&](int row, int p) {
    int r = (row > rowmax) ? rowmax : row;
    const float* rp = rowptr(r);
#pragma unroll
    for (int j = 0; j < SPT; ++j) PF[p][j] = rp[off[j]];
    NLS[p] = -lse2[r * B_BATCH + b];
  };

  double prev1, prev2;
  const bool l0 = (lane == 0);

  auto step = [&](int p) {
    double pv[SPT];
#pragma unroll
    for (int j = 0; j < SPT; ++j) pv[j] = (double)exp2f(fmaf(PF[p][j], L2E, NLS[p]));
    double n5 = fma(m2[5], a[3], a[5] + a[4]) * pv[5];
    double n6 = fma(m2[6], a[4], a[6] + a[5]) * pv[6];
    double n0 = fma(m2[0], prev2, a[0] + prev1) * pv[0];
    double n1 = fma(m2[1], prev1, a[1] + a[0]) * pv[1];
    double n2 = fma(m2[2], a[0], a[2] + a[1]) * pv[2];
    double n3 = fma(m2[3], a[1], a[3] + a[2]) * pv[3];
    double n4 = fma(m2[4], a[2], a[4] + a[3]) * pv[4];
    a[5] = n5; a[6] = n6;
    double np1 = __shfl_up(a[6], 1, 64);
    double np2 = __shfl_up(a[5], 1, 64);
    a[0] = n0; a[1] = n1; a[2] = n2; a[3] = n3; a[4] = n4;
    prev1 = l0 ? 0.0 : np1;
    prev2 = l0 ? 0.0 : np2;
  };

  int LS = 0;
  auto renorm = [&]() {
    double m = a[0];
#pragma unroll
    for (int j = 1; j < SPT; ++j) m = fmax(m, a[j]);
    int eb = (int)(__double_as_longlong(m) >> 52);
    eb = wave_reduce_max_i(eb);
    int sc = (eb - 1022) - EBIAS;
#pragma unroll
    for (int j = 0; j < SPT; ++j) a[j] = ldexp(a[j], -sc);
    prev1 = ldexp(prev1, -sc);
    prev2 = ldexp(prev2, -sc);
    LS += sc;
  };

#pragma unroll
  for (int d = 0; d < PFD; ++d) issue(1 + d, d);
  {
    double np1 = __shfl_up(a[SPT - 1], 1, 64);
    double np2 = __shfl_up(a[SPT - 2], 1, 64);
    prev1 = l0 ? 0.0 : np1;
    prev2 = l0 ? 0.0 : np2;
  }

  int t = 1;
  while (t + PFD <= act_len) {
#pragma unroll
    for (int p = 0; p < PFD; ++p) { step(p); issue(t + p + PFD, p); }
    t += PFD;
    renorm();
  }
#pragma unroll
  for (int p = 0; p < PFD; ++p) {
    if (t + p < act_len) step(p);
  }

  __shared__ double sh[64 * SPT];
#pragma unroll
  for (int j = 0; j < SPT; ++j) sh[lane * SPT + j] = a[j];
  __syncthreads();
  if (lane == 0) {
    double ae = sh[send];
    double ap = (LL > 0) ? sh[send - 1] : 0.0;
    double s = ae + ap;
    losses[b] = (float)(-(log2(s) + (double)LS) * LN2D);
  }
}

__global__ __launch_bounds__(64) void finalize_kernel(const float* __restrict__ losses,
                                                      const int* __restrict__ act_lens,
                                                      float* __restrict__ out) {
  int lane = threadIdx.x;  // B == 64 exactly
  float l = losses[lane];
  float n = (float)act_lens[lane];
  l = wave_reduce_sum(l);
  n = wave_reduce_sum(n);
  if (lane == 0) out[0] = l / n;
}

extern "C" void kernel_launch(void* const* d_in, const int* in_sizes, int n_in,
                              void* d_out, int out_size, void* d_ws, size_t ws_size,
                              hipStream_t stream) {
  const float* logits = (const float*)d_in[0];
  const int* labels = (const int*)d_in[1];
  const int* act_lens = (const int*)d_in[2];
  const int* label_lens = (const int*)d_in[3];
  float* out = (float*)d_out;

  const size_t probs_bytes = (size_t)B_BATCH * T_FRAMES * V_VOCAB * sizeof(float);
  const int rows = T_FRAMES * B_BATCH;
  const int sm_grid = (rows + 3) / 4;

  if (ws_size >= probs_bytes + 1024) {
    float* probs = (float*)d_ws;
    float* losses = (float*)((char*)d_ws + probs_bytes);
    softmax_tr_kernel<<<dim3(sm_grid), dim3(256), 0, stream>>>(logits, probs);
    ctc_kernel_probs<<<dim3(B_BATCH), dim3(64), 0, stream>>>(probs, labels,
                                                             act_lens, label_lens, losses);
    finalize_kernel<<<dim3(1), dim3(64), 0, stream>>>(losses, act_lens, out);
  } else {
    float* lse2 = (float*)d_ws;  // rows floats = 512 KB
    float* losses = (float*)((char*)d_ws + (size_t)rows * sizeof(float));
    lse_kernel<<<dim3(sm_grid), dim3(256), 0, stream>>>(logits, lse2);
    ctc_kernel_lse<<<dim3(B_BATCH), dim3(64), 0, stream>>>(logits, lse2, labels,
                                                           act_lens, label_lens, losses);
    finalize_kernel<<<dim3(1), dim3(64), 0, stream>>>(losses, act_lens, out);
  }
}